// Round 11
// baseline (225.199 us; speedup 1.0000x reference)
//
#include <hip/hip_runtime.h>
#include <hip/hip_bf16.h>
#include <stdint.h>

// Problem constants (from reference)
#define H   128
#define NM  5000
#define NO  100000
#define EA  1000000
#define EC  500000
#define ET  1000000
#define EL  500000

typedef __hip_bfloat16 bf16;
typedef float v2f __attribute__((ext_vector_type(2)));

// main kernel partition: gine_a | gine_c | sage_tv | sage_log | means | warm
#define B_GA 512
#define B_GC 256
#define B_TV 512
#define B_LG 256
#define B_MN 48
#define B_WM 6
#define MAIN_BLOCKS (B_GA + B_GC + B_TV + B_LG + B_MN + B_WM)

// histogram config
#define C_M 128           // cnt_m chunk blocks (full 5000-bin hist each)
#define R_O 8             // cnt_o bin ranges
#define RSZ 12800         // bins per range
#define C_O 16            // cnt_o edge chunks
#define NOP 102400        // padded cnt_o bins
#define HIST_BLOCKS (1 + C_M + R_O * C_O)
#define MERGE_M_BLK 20
#define MERGE_BLOCKS (MERGE_M_BLK + NOP / 256)

struct Par {
    const void *x_m, *x_o, *ea_a, *ea_c;
    const int *ei_a, *ei_c, *ei_tv, *ei_log;
    const void *Wm, *bm, *Wo, *bo;
    const void *Wn_a, *bn_a, *We_a, *be_a;
    const void *Wn_c, *bn_c, *We_c, *be_c;
    const void *Wl_tv, *bl_tv, *Wr_tv, *Wl_log, *bl_log, *Wr_log;
    int *cnt_m, *cnt_o;
    uint16_t *part_hm, *part_ho;
    float *part_a, *part_c, *part_tv, *part_lg, *part_mn;
    int *flagw;
    const int *flag;
    void *out;
};

// ---- dtype-flexible loads ----
template<bool ISF32>
__device__ __forceinline__ float ldf(const void* p, int i) {
    if constexpr (ISF32) return ((const float*)p)[i];
    else                 return __bfloat162float(((const bf16*)p)[i]);
}

__device__ __forceinline__ float bflo(uint32_t v) {
    union { uint32_t u; float f; } c; c.u = v << 16; return c.f;
}
__device__ __forceinline__ float bfhi(uint32_t v) {
    union { uint32_t u; float f; } c; c.u = v & 0xFFFF0000u; return c.f;
}

template<bool ISF32>
__device__ __forceinline__ float4 ld4(const void* p, int row) {
    if constexpr (ISF32) return ((const float4*)p)[row];
    else {
        const uint2 t = ((const uint2*)p)[row];
        float4 r; r.x = bflo(t.x); r.y = bfhi(t.x); r.z = bflo(t.y); r.w = bfhi(t.y);
        return r;
    }
}

__device__ __forceinline__ float wred(float v) {
#pragma unroll
    for (int o = 32; o; o >>= 1) v += __shfl_down(v, o, 64);
    return v;
}

// ---- phase A: detect + private histograms (no global atomics) ----
__global__ __launch_bounds__(256) void hist_kernel(const Par p) {
    __shared__ int hist[RSZ];   // 51200 B
    const int t = threadIdx.x;
    const int b = blockIdx.x;
    if (b == 0) {
        int local = 0;
        const uint16_t* xm = (const uint16_t*)p.x_m;
        for (int i = t; i < 15000; i += 256)
            if (((xm[i] >> 7) & 0xFF) == 0xFF) local = 1;
        if (t == 0) hist[0] = 0;
        __syncthreads();
        if (local) atomicOr(&hist[0], 1);
        __syncthreads();
        if (t == 0) *p.flagw = hist[0];
    } else if (b <= C_M) {
        // cnt_m chunk histogram: 5000 bins, ~7813 edges per block
        const int c = b - 1;
        for (int i = t; i < NM; i += 256) hist[i] = 0;
        __syncthreads();
        const int* dst = p.ei_tv + ET;
        const int chunk = (ET + C_M - 1) / C_M;
        const int e0 = c * chunk;
        int e1 = e0 + chunk; if (e1 > ET) e1 = ET;
        for (int i = e0 + t; i < e1; i += 256)
            atomicAdd(&hist[dst[i]], 1);
        __syncthreads();
        uint16_t* outp = p.part_hm + c * NM;
        for (int i = t; i < NM; i += 256) outp[i] = (uint16_t)hist[i];
    } else {
        // cnt_o range-filtered histogram: range r, chunk c (int2 loads)
        const int idx = b - 1 - C_M;
        const int r = idx / C_O, c = idx % C_O;
        const int lo = r * RSZ;
        for (int i = t; i < RSZ; i += 256) hist[i] = 0;
        __syncthreads();
        const int2* dst2 = (const int2*)(p.ei_log + EL);
        const int base = c * (EL / C_O / 2);
        for (int i = t; i < EL / C_O / 2; i += 256) {
            const int2 d = dst2[base + i];
            unsigned q;
            q = (unsigned)(d.x - lo); if (q < RSZ) atomicAdd(&hist[q], 1);
            q = (unsigned)(d.y - lo); if (q < RSZ) atomicAdd(&hist[q], 1);
        }
        __syncthreads();
        uint16_t* outp = p.part_ho + c * NOP + lo;
        for (int i = t; i < RSZ; i += 256) outp[i] = (uint16_t)hist[i];
    }
}

// ---- phase B: merge histograms -> counts ----
__global__ __launch_bounds__(256) void merge_kernel(const Par p) {
    const int t = threadIdx.x;
    const int b = blockIdx.x;
    if (b < MERGE_M_BLK) {
        const int bin = b * 256 + t;
        if (bin < NM) {
            int s = 0;
#pragma unroll 16
            for (int c = 0; c < C_M; ++c) s += p.part_hm[c * NM + bin];
            p.cnt_m[bin] = s;
        }
    } else {
        const int bin = (b - MERGE_M_BLK) * 256 + t;
        int s = 0;
#pragma unroll
        for (int c = 0; c < C_O; ++c) s += p.part_ho[c * NOP + bin];
        p.cnt_o[bin] = s;
    }
}

// ---- GINE: coalesced stage (2 edges/lane) -> fp32 LDS broadcast -> pk-fma ----
// 128-edge granules: doubled gather MLP, halved loop overhead vs r7/r10.
template<int FIN, int ED, bool ISF32>
__device__ __forceinline__ void gine_body(
    const int* __restrict__ src, const void* __restrict__ ea,
    const void* __restrict__ x, const void* __restrict__ We,
    const void* __restrict__ be, const void* __restrict__ Wx,
    const void* __restrict__ bx, float* __restrict__ part,
    int E, int relb, int nblk, float* stage, float* r0, float* r1)
{
    constexpr int KT = FIN + ED;
    const int lane = threadIdx.x & 63;
    const int wv = threadIdx.x >> 6;
    const int c0 = 2 * lane;
    v2f wc[KT];
#pragma unroll
    for (int k = 0; k < FIN; ++k)
        wc[k] = (v2f){ldf<ISF32>(Wx, k * H + c0), ldf<ISF32>(Wx, k * H + c0 + 1)};
#pragma unroll
    for (int k = 0; k < ED; ++k)
        wc[FIN + k] = (v2f){ldf<ISF32>(We, k * H + c0), ldf<ISF32>(We, k * H + c0 + 1)};
    const v2f bb = (v2f){ldf<ISF32>(bx, c0) + ldf<ISF32>(be, c0),
                         ldf<ISF32>(bx, c0 + 1) + ldf<ISF32>(be, c0 + 1)};

    float* myst = stage + wv * 1024;             // 128 edges x 8 floats
    const float4* rd4 = (const float4*)myst;

    v2f acc = (v2f){0.f, 0.f};
    const int G = (E + 127) >> 7;
    const int NW = nblk * 4;
    for (int g = relb * 4 + wv; g < G; g += NW) {
        const int base = g << 7;
        const int ecnt = min(128, E - base);
        // stage 2 edges per lane (independent gathers, all in flight)
#pragma unroll
        for (int h = 0; h < 2; ++h) {
            const int j = h * 64 + lane;
            const int ej = base + (j < ecnt ? j : ecnt - 1);
            float f[8];
#pragma unroll
            for (int k = 0; k < 8; ++k) f[k] = 0.f;
            const int s = src[ej];
            if constexpr (FIN == 4) {
                const float4 xv = ld4<ISF32>(x, s);
                f[0] = xv.x; f[1] = xv.y; f[2] = xv.z; f[3] = xv.w;
            } else {
#pragma unroll
                for (int k = 0; k < FIN; ++k) f[k] = ldf<ISF32>(x, s * FIN + k);
            }
#pragma unroll
            for (int k = 0; k < ED; ++k) f[FIN + k] = ldf<ISF32>(ea, ej * ED + k);
            float4* st4 = (float4*)(myst + j * 8);
            st4[0] = (float4){f[0], f[1], f[2], f[3]};
            st4[1] = (float4){f[4], f[5], f[6], f[7]};
        }
        // broadcast-compute over staged edges (compiler inserts lgkmcnt wait)
#pragma unroll 2
        for (int jj = 0; jj < ecnt; ++jj) {
            float fe[8];
            {
                const float4 lo = rd4[jj * 2];
                fe[0] = lo.x; fe[1] = lo.y; fe[2] = lo.z; fe[3] = lo.w;
            }
            if constexpr (KT > 4) {
                const float4 hi = rd4[jj * 2 + 1];
                fe[4] = hi.x; fe[5] = hi.y; fe[6] = hi.z; fe[7] = hi.w;
            }
            v2f m = bb;
#pragma unroll
            for (int k = 0; k < KT; ++k)
                m += wc[k] * (v2f){fe[k], fe[k]};
            m.x = fmaxf(m.x, 0.f);
            m.y = fmaxf(m.y, 0.f);
            acc += m;
        }
    }
    r0[threadIdx.x] = acc.x; r1[threadIdx.x] = acc.y;
    __syncthreads();
    if (threadIdx.x < 64) {
        const int l = threadIdx.x;
        float s0 = r0[l] + r0[l + 64] + r0[l + 128] + r0[l + 192];
        float s1 = r1[l] + r1[l + 64] + r1[l + 128] + r1[l + 192];
        part[2 * l]     = s0;
        part[2 * l + 1] = s1;
    }
}

// ---- component sums of x over nodes ----
template<int FIN, bool ISF32>
__device__ __forceinline__ void mean_body(
    const void* __restrict__ x, float* __restrict__ part, int N,
    int relb, int nblk, float* lds)
{
    const int stride = nblk * 256;
    float acc[FIN];
#pragma unroll
    for (int k = 0; k < FIN; ++k) acc[k] = 0.f;
    for (int n = relb * 256 + threadIdx.x; n < N; n += stride) {
        if constexpr (FIN == 4) {
            const float4 xv = ld4<ISF32>(x, n);
            acc[0] += xv.x; acc[1] += xv.y; acc[2] += xv.z; acc[3] += xv.w;
        } else {
#pragma unroll
            for (int k = 0; k < FIN; ++k) acc[k] += ldf<ISF32>(x, n * FIN + k);
        }
    }
#pragma unroll
    for (int k = 0; k < FIN; ++k) acc[k] = wred(acc[k]);
    if ((threadIdx.x & 63) == 0) {
        const int w = threadIdx.x >> 6;
#pragma unroll
        for (int k = 0; k < 4; ++k) lds[w * 4 + k] = (k < FIN) ? acc[k] : 0.f;
    }
    __syncthreads();
    if (threadIdx.x < 4)
        part[threadIdx.x] = lds[threadIdx.x] + lds[4 + threadIdx.x]
                          + lds[8 + threadIdx.x] + lds[12 + threadIdx.x];
}

// ---- SAGE edge reduction, int4-batched ----
template<bool ISF32>
__device__ __forceinline__ void sage_body(
    const void* __restrict__ x, const int* __restrict__ src,
    const int* __restrict__ dst, const int* __restrict__ cnt,
    float* __restrict__ part, int E, int relb, int nblk, float* lds)
{
    const int tid = threadIdx.x;
    const int nv = E >> 2;
    const int stride = nblk * 256;
    float a0 = 0.f, a1 = 0.f, a2 = 0.f, a3 = 0.f, aw = 0.f;
#pragma unroll 2
    for (int i = relb * 256 + tid; i < nv; i += stride) {
        const int4 s4 = ((const int4*)src)[i];
        const int4 d4 = ((const int4*)dst)[i];
        const int c0 = cnt[d4.x], c1 = cnt[d4.y], c2 = cnt[d4.z], c3 = cnt[d4.w];
        const float4 x0 = ld4<ISF32>(x, s4.x);
        const float4 x1 = ld4<ISF32>(x, s4.y);
        const float4 x2 = ld4<ISF32>(x, s4.z);
        const float4 x3 = ld4<ISF32>(x, s4.w);
        const float i0 = __builtin_amdgcn_rcpf((float)(c0 > 0 ? c0 : 1));
        const float i1 = __builtin_amdgcn_rcpf((float)(c1 > 0 ? c1 : 1));
        const float i2 = __builtin_amdgcn_rcpf((float)(c2 > 0 ? c2 : 1));
        const float i3 = __builtin_amdgcn_rcpf((float)(c3 > 0 ? c3 : 1));
        a0 = fmaf(i0, x0.x, a0); a1 = fmaf(i0, x0.y, a1); a2 = fmaf(i0, x0.z, a2); a3 = fmaf(i0, x0.w, a3); aw += i0;
        a0 = fmaf(i1, x1.x, a0); a1 = fmaf(i1, x1.y, a1); a2 = fmaf(i1, x1.z, a2); a3 = fmaf(i1, x1.w, a3); aw += i1;
        a0 = fmaf(i2, x2.x, a0); a1 = fmaf(i2, x2.y, a1); a2 = fmaf(i2, x2.z, a2); a3 = fmaf(i2, x2.w, a3); aw += i2;
        a0 = fmaf(i3, x3.x, a0); a1 = fmaf(i3, x3.y, a1); a2 = fmaf(i3, x3.z, a2); a3 = fmaf(i3, x3.w, a3); aw += i3;
    }
    a0 = wred(a0); a1 = wred(a1); a2 = wred(a2); a3 = wred(a3); aw = wred(aw);
    if ((tid & 63) == 0) {
        float* w5 = lds + (tid >> 6) * 5;
        w5[0] = a0; w5[1] = a1; w5[2] = a2; w5[3] = a3; w5[4] = aw;
    }
    __syncthreads();
    if (tid < 5)
        part[tid] = lds[tid] + lds[5 + tid] + lds[10 + tid] + lds[15 + tid];
}

// ---- warm: stream final-kernel weights into L2/L3 ----
__device__ __forceinline__ void warm_body(const Par p, int rb, bool f32, float* lds) {
    const void* w[6] = {p.Wn_a, p.Wn_c, p.Wl_tv, p.Wr_tv, p.Wl_log, p.Wr_log};
    const uint4* u = (const uint4*)w[rb];
    const int n16 = (f32 ? (H * H * 4) : (H * H * 2)) / 16;
    uint32_t s = 0;
    for (int i = threadIdx.x; i < n16; i += 256) {
        const uint4 v = u[i];
        s ^= v.x ^ v.y ^ v.z ^ v.w;
    }
    lds[threadIdx.x] = (float)(s & 1);
    __syncthreads();
    if (threadIdx.x == 0) {
        float acc = 0.f;
        for (int i = 0; i < 256; ++i) acc += lds[i];
        p.part_mn[(48 + rb) * 4] = acc;   // dummy sink (rows >= 48 unused)
    }
}

// ---- main: gine_a | gine_c | sage_tv | sage_log | means | warm ----
template<bool ISF32>
__device__ __forceinline__ void main_body(const Par p, float* smem) {
    const int b = blockIdx.x;
    if (b < B_GA) {
        gine_body<3, 3, ISF32>(p.ei_a, p.ea_a, p.x_m, p.We_a, p.be_a, p.Wm, p.bm,
                               p.part_a + b * H, EA, b, B_GA,
                               smem, smem + 4096, smem + 4352);
    } else if (b < B_GA + B_GC) {
        const int rb = b - B_GA;
        gine_body<4, 1, ISF32>(p.ei_c, p.ea_c, p.x_o, p.We_c, p.be_c, p.Wo, p.bo,
                               p.part_c + rb * H, EC, rb, B_GC,
                               smem, smem + 4096, smem + 4352);
    } else if (b < B_GA + B_GC + B_TV) {
        const int rb = b - (B_GA + B_GC);
        sage_body<ISF32>(p.x_o, p.ei_tv, p.ei_tv + ET, p.cnt_m,
                         p.part_tv + rb * 8, ET, rb, B_TV, smem);
    } else if (b < B_GA + B_GC + B_TV + B_LG) {
        const int rb = b - (B_GA + B_GC + B_TV);
        sage_body<ISF32>(p.x_o, p.ei_log, p.ei_log + EL, p.cnt_o,
                         p.part_lg + rb * 8, EL, rb, B_LG, smem);
    } else if (b < B_GA + B_GC + B_TV + B_LG + B_MN) {
        const int rb = b - (B_GA + B_GC + B_TV + B_LG);
        if (rb < 8) mean_body<3, ISF32>(p.x_m, p.part_mn + rb * 4, NM, rb, 8, smem);
        else        mean_body<4, ISF32>(p.x_o, p.part_mn + rb * 4, NO, rb - 8, 40, smem);
    } else {
        warm_body(p, b - (B_GA + B_GC + B_TV + B_LG + B_MN), ISF32, smem);
    }
}

__global__ __launch_bounds__(256) void main_kernel(const Par p) {
    __shared__ __align__(16) float smem[4608];  // stage 16KB + r0/r1 2KB
    if (*p.flag) main_body<true >(p, smem);
    else         main_body<false>(p, smem);
}

// ---- final: 2 blocks. block 0 -> g_m, block 1 -> g_o (direct fold) ----
template<bool ISF32>
__device__ __forceinline__ void final_body(const Par p) {
    __shared__ float scal[17];       // [0..3]twx [4]tsw [5..8]lwx [9]lsw [10..12]xm [13..16]xo
    __shared__ float seg[5][8];
    __shared__ float sh2a[2][H], sh2c[2][H];
    __shared__ float va[H], vb[H], vc2[H], vd[H];
    __shared__ float matp[256];
    const int t = threadIdx.x;

    if (blockIdx.x == 0) {
        // ---- g_m ----
        if (t < 40) {
            const int k = t >> 3, sg = t & 7;
            float s = 0.f;
            const int r0 = sg * (B_TV / 8);
#pragma unroll 8
            for (int r = r0; r < r0 + B_TV / 8; ++r) s += p.part_tv[r * 8 + k];
            seg[k][sg] = s;
        } else if (t >= 64 && t < 67) {
            const int k = t - 64;
            float s = 0.f;
            for (int r = 0; r < 8; ++r) s += p.part_mn[r * 4 + k];
            scal[10 + k] = s;
        }
        __syncthreads();
        if (t < 5) {
            float s = 0.f;
#pragma unroll
            for (int g = 0; g < 8; ++g) s += seg[t][g];
            scal[t] = s;
        }
        __syncthreads();
        if (t < H) {
            float mhm = ldf<ISF32>(p.bm, t);
#pragma unroll
            for (int k = 0; k < 3; ++k)
                mhm = fmaf(scal[10 + k] * (1.f / NM), ldf<ISF32>(p.Wm, k * H + t), mhm);
            float tv = scal[4] * ldf<ISF32>(p.bo, t);
#pragma unroll
            for (int k = 0; k < 4; ++k)
                tv = fmaf(scal[k], ldf<ISF32>(p.Wo, k * H + t), tv);
            va[t] = tv * (1.f / NM);   // vtv
            vb[t] = mhm;               // vmhm
        }
        __syncthreads();
        {
            const int half = t >> 7, tt = t & 127;
            float acc = (half == 0) ? ldf<ISF32>(p.bl_tv, tt) : 0.f;
            const int k0 = half * 64;
#pragma unroll 8
            for (int k = k0; k < k0 + 64; ++k) {
                acc = fmaf(va[k], ldf<ISF32>(p.Wl_tv, k * H + tt), acc);
                acc = fmaf(vb[k], ldf<ISF32>(p.Wr_tv, k * H + tt), acc);
            }
            matp[t] = acc;
        }
        __syncthreads();
        if (t < H) {
            const float r = matp[t] + matp[t + 128];
            if constexpr (ISF32) ((float*)p.out)[t] = r;
            else                 ((bf16*)p.out)[t] = __float2bfloat16(r);
        }
    } else {
        // ---- g_o ----
        {   // direct column fold of part_a (512 rows) + part_c (256 rows)
            const int col = t & 127, half = t >> 7;
            float sA = 0.f;
            const float* pa = p.part_a + (half * (B_GA / 2)) * H + col;
#pragma unroll 8
            for (int r = 0; r < B_GA / 2; ++r) sA += pa[r * H];
            sh2a[half][col] = sA;
            float sC = 0.f;
            const float* pc = p.part_c + (half * (B_GC / 2)) * H + col;
#pragma unroll 8
            for (int r = 0; r < B_GC / 2; ++r) sC += pc[r * H];
            sh2c[half][col] = sC;
        }
        if (t < 40) {
            const int k = t >> 3, sg = t & 7;
            float s = 0.f;
            const int r0 = sg * (B_LG / 8);
#pragma unroll 8
            for (int r = r0; r < r0 + B_LG / 8; ++r) s += p.part_lg[r * 8 + k];
            seg[k][sg] = s;
        } else if (t >= 64 && t < 68) {
            const int k = t - 64;
            float s = 0.f;
#pragma unroll 8
            for (int r = 8; r < 48; ++r) s += p.part_mn[r * 4 + k];
            scal[13 + k] = s;
        }
        __syncthreads();
        if (t < 5) {
            float s = 0.f;
#pragma unroll
            for (int g = 0; g < 8; ++g) s += seg[t][g];
            scal[5 + t] = s;
        }
        __syncthreads();
        if (t < H) {
            float mho = ldf<ISF32>(p.bo, t);
#pragma unroll
            for (int k = 0; k < 4; ++k)
                mho = fmaf(scal[13 + k] * (1.f / NO), ldf<ISF32>(p.Wo, k * H + t), mho);
            float lg = scal[9] * ldf<ISF32>(p.bo, t);
#pragma unroll
            for (int k = 0; k < 4; ++k)
                lg = fmaf(scal[5 + k], ldf<ISF32>(p.Wo, k * H + t), lg);
            const float sha = sh2a[0][t] + sh2a[1][t];
            const float shc = sh2c[0][t] + sh2c[1][t];
            va[t]  = sha * (1.f / NO) + mho;   // GINE-a vector
            vb[t]  = shc * (1.f / NO) + mho;   // GINE-c vector
            vc2[t] = lg * (1.f / NO);          // vlog
            vd[t]  = mho;                      // vmho
        }
        __syncthreads();
        {
            const int half = t >> 7, tt = t & 127;
            float acc = (half == 0)
                ? ldf<ISF32>(p.bn_a, tt) + ldf<ISF32>(p.bn_c, tt) + ldf<ISF32>(p.bl_log, tt)
                : 0.f;
            const int k0 = half * 64;
#pragma unroll 8
            for (int k = k0; k < k0 + 64; ++k) {
                acc = fmaf(va[k],  ldf<ISF32>(p.Wn_a, k * H + tt), acc);
                acc = fmaf(vb[k],  ldf<ISF32>(p.Wn_c, k * H + tt), acc);
                acc = fmaf(vc2[k], ldf<ISF32>(p.Wl_log, k * H + tt), acc);
                acc = fmaf(vd[k],  ldf<ISF32>(p.Wr_log, k * H + tt), acc);
            }
            matp[t] = acc;
        }
        __syncthreads();
        if (t < H) {
            const float r = (matp[t] + matp[t + 128]) * (1.f / 3.f);
            if constexpr (ISF32) ((float*)p.out)[H + t] = r;
            else                 ((bf16*)p.out)[H + t] = __float2bfloat16(r);
        }
    }
}

__global__ __launch_bounds__(256) void final_kernel(const Par p) {
    if (*p.flag) final_body<true >(p);
    else         final_body<false>(p);
}

extern "C" void kernel_launch(void* const* d_in, const int* in_sizes, int n_in,
                              void* d_out, int out_size, void* d_ws, size_t ws_size,
                              hipStream_t stream) {
    char* ws = (char*)d_ws;
    Par p;
    p.x_m   = d_in[0];  p.x_o   = d_in[1];
    p.ea_a  = d_in[2];  p.ea_c  = d_in[3];
    p.ei_a  = (const int*)d_in[4];
    p.ei_c  = (const int*)d_in[5];
    p.ei_tv = (const int*)d_in[6];
    p.ei_log= (const int*)d_in[7];
    p.Wm = d_in[8];  p.bm = d_in[9];  p.Wo = d_in[10]; p.bo = d_in[11];
    p.Wn_a = d_in[12]; p.bn_a = d_in[13]; p.We_a = d_in[14]; p.be_a = d_in[15];
    p.Wn_c = d_in[16]; p.bn_c = d_in[17]; p.We_c = d_in[18]; p.be_c = d_in[19];
    p.Wl_tv = d_in[20]; p.bl_tv = d_in[21]; p.Wr_tv = d_in[22];
    p.Wl_log = d_in[23]; p.bl_log = d_in[24]; p.Wr_log = d_in[25];

    // Workspace layout (bytes); every region fully written by its owner:
    //   [0,        20480)    cnt_m   int[5000] (padded)
    //   [20480,    430080)   cnt_o   int[102400]
    //   [430080,   430084)   flag
    //   [430592,   1710592)  part_hm u16[128][5000]
    //   [1710592,  4987392)  part_ho u16[16][102400]
    //   [4987392,  5249536)  part_a  float[512][128]
    //   [5249536,  5380608)  part_c  float[256][128]
    //   [5380608,  5396992)  part_tv float[512][8]
    //   [5396992,  5405184)  part_lg float[256][8]
    //   [5405184,  5406048)  part_mn float[54][4]
    p.cnt_m   = (int*)(ws);
    p.cnt_o   = (int*)(ws + 20480);
    p.flagw   = (int*)(ws + 430080);
    p.flag    = p.flagw;
    p.part_hm = (uint16_t*)(ws + 430592);
    p.part_ho = (uint16_t*)(ws + 1710592);
    p.part_a  = (float*)(ws + 4987392);
    p.part_c  = (float*)(ws + 5249536);
    p.part_tv = (float*)(ws + 5380608);
    p.part_lg = (float*)(ws + 5396992);
    p.part_mn = (float*)(ws + 5405184);
    p.out  = d_out;

    hist_kernel<<<HIST_BLOCKS, 256, 0, stream>>>(p);    // detect + private hists
    merge_kernel<<<MERGE_BLOCKS, 256, 0, stream>>>(p);  // counts (atomic-free)
    main_kernel<<<MAIN_BLOCKS, 256, 0, stream>>>(p);    // gine + sage + means + warm
    final_kernel<<<2, 256, 0, stream>>>(p);             // fold + mat-vecs
}

// Round 12
// 214.461 us; speedup vs baseline: 1.0501x; 1.0501x over previous
//
#include <hip/hip_runtime.h>
#include <hip/hip_bf16.h>
#include <stdint.h>

// Problem constants (from reference)
#define H   128
#define NM  5000
#define NO  100000
#define EA  1000000
#define EC  500000
#define ET  1000000
#define EL  500000

typedef __hip_bfloat16 bf16;
typedef float f32x4 __attribute__((ext_vector_type(4)));
typedef short short8 __attribute__((ext_vector_type(8)));

// main kernel partition: gine_a | gine_c | sage_tv | sage_log | means | warm
#define B_GA 512
#define B_GC 256
#define B_TV 512
#define B_LG 256
#define B_MN 48
#define B_WM 6
#define MAIN_BLOCKS (B_GA + B_GC + B_TV + B_LG + B_MN + B_WM)

// histogram config
#define C_M 128
#define R_O 8
#define RSZ 12800
#define C_O 16
#define NOP 102400
#define HIST_BLOCKS (1 + C_M + R_O * C_O)
#define MERGE_M_BLK 20
#define MERGE_BLOCKS (MERGE_M_BLK + NOP / 256)

struct Par {
    const void *x_m, *x_o, *ea_a, *ea_c;
    const int *ei_a, *ei_c, *ei_tv, *ei_log;
    const void *Wm, *bm, *Wo, *bo;
    const void *Wn_a, *bn_a, *We_a, *be_a;
    const void *Wn_c, *bn_c, *We_c, *be_c;
    const void *Wl_tv, *bl_tv, *Wr_tv, *Wl_log, *bl_log, *Wr_log;
    int *cnt_m, *cnt_o;
    uint16_t *part_hm, *part_ho;
    float *part_a, *part_c, *part_tv, *part_lg, *part_mn;
    float *part_a2, *part_c2;
    int *flagw;
    const int *flag;
    void *out;
};

// ---- dtype-flexible loads ----
template<bool ISF32>
__device__ __forceinline__ float ldf(const void* p, int i) {
    if constexpr (ISF32) return ((const float*)p)[i];
    else                 return __bfloat162float(((const bf16*)p)[i]);
}

__device__ __forceinline__ float bflo(uint32_t v) {
    union { uint32_t u; float f; } c; c.u = v << 16; return c.f;
}
__device__ __forceinline__ float bfhi(uint32_t v) {
    union { uint32_t u; float f; } c; c.u = v & 0xFFFF0000u; return c.f;
}

__device__ __forceinline__ uint32_t pack2(float a, float b) {
    union { bf16 h; uint16_t u; } ca, cb;
    ca.h = __float2bfloat16(a); cb.h = __float2bfloat16(b);
    return (uint32_t)ca.u | ((uint32_t)cb.u << 16);
}

__device__ __forceinline__ uint16_t bfbits(float a) {
    union { bf16 h; uint16_t u; } c; c.h = __float2bfloat16(a); return c.u;
}

template<bool ISF32>
__device__ __forceinline__ float4 ld4(const void* p, int row) {
    if constexpr (ISF32) return ((const float4*)p)[row];
    else {
        const uint2 t = ((const uint2*)p)[row];
        float4 r; r.x = bflo(t.x); r.y = bfhi(t.x); r.z = bflo(t.y); r.w = bfhi(t.y);
        return r;
    }
}

__device__ __forceinline__ float wred(float v) {
#pragma unroll
    for (int o = 32; o; o >>= 1) v += __shfl_down(v, o, 64);
    return v;
}

// ---- phase A: detect + private histograms (no global atomics) ----
__global__ __launch_bounds__(256) void hist_kernel(const Par p) {
    __shared__ int hist[RSZ];
    const int t = threadIdx.x;
    const int b = blockIdx.x;
    if (b == 0) {
        int local = 0;
        const uint16_t* xm = (const uint16_t*)p.x_m;
        for (int i = t; i < 15000; i += 256)
            if (((xm[i] >> 7) & 0xFF) == 0xFF) local = 1;
        if (t == 0) hist[0] = 0;
        __syncthreads();
        if (local) atomicOr(&hist[0], 1);
        __syncthreads();
        if (t == 0) *p.flagw = hist[0];
    } else if (b <= C_M) {
        const int c = b - 1;
        for (int i = t; i < NM; i += 256) hist[i] = 0;
        __syncthreads();
        const int* dst = p.ei_tv + ET;
        const int chunk = (ET + C_M - 1) / C_M;
        const int e0 = c * chunk;
        int e1 = e0 + chunk; if (e1 > ET) e1 = ET;
        for (int i = e0 + t; i < e1; i += 256)
            atomicAdd(&hist[dst[i]], 1);
        __syncthreads();
        uint16_t* outp = p.part_hm + c * NM;
        for (int i = t; i < NM; i += 256) outp[i] = (uint16_t)hist[i];
    } else {
        const int idx = b - 1 - C_M;
        const int r = idx / C_O, c = idx % C_O;
        const int lo = r * RSZ;
        for (int i = t; i < RSZ; i += 256) hist[i] = 0;
        __syncthreads();
        const int2* dst2 = (const int2*)(p.ei_log + EL);
        const int base = c * (EL / C_O / 2);
        for (int i = t; i < EL / C_O / 2; i += 256) {
            const int2 d = dst2[base + i];
            unsigned q;
            q = (unsigned)(d.x - lo); if (q < RSZ) atomicAdd(&hist[q], 1);
            q = (unsigned)(d.y - lo); if (q < RSZ) atomicAdd(&hist[q], 1);
        }
        __syncthreads();
        uint16_t* outp = p.part_ho + c * NOP + lo;
        for (int i = t; i < RSZ; i += 256) outp[i] = (uint16_t)hist[i];
    }
}

// ---- phase B: merge histograms -> counts ----
__global__ __launch_bounds__(256) void merge_kernel(const Par p) {
    const int t = threadIdx.x;
    const int b = blockIdx.x;
    if (b < MERGE_M_BLK) {
        const int bin = b * 256 + t;
        if (bin < NM) {
            int s = 0;
#pragma unroll 16
            for (int c = 0; c < C_M; ++c) s += p.part_hm[c * NM + bin];
            p.cnt_m[bin] = s;
        }
    } else {
        const int bin = (b - MERGE_M_BLK) * 256 + t;
        int s = 0;
#pragma unroll
        for (int c = 0; c < C_O; ++c) s += p.part_ho[c * NOP + bin];
        p.cnt_o[bin] = s;
    }
}

// ---- GINE via MFMA, occupancy-safe (channels split across waves) ----
// Granule = 256 edges staged once per block (bf16, double-buffered).
// F[256][8]: features + edge-attrs + constant-1 column (bias = W-row KT,
// zero-padded rows contribute 0). Wave w owns channels [32w, 32w+32):
// 2 N-tiles -> 8 acc + 8 B-frag VGPRs (vs 64 in the r9 variant).
// A-layout A[m=lane&15][k=quad*8+j]; C/D col=lane&15, row=quad*4+reg
// (numerics verified end-to-end by r9: absmax 0.0156).
template<int FIN, int ED, bool ISF32>
__device__ __forceinline__ void gine_body(
    const int* __restrict__ src, const void* __restrict__ ea,
    const void* __restrict__ x, const void* __restrict__ We,
    const void* __restrict__ be, const void* __restrict__ Wx,
    const void* __restrict__ bx, float* __restrict__ part,
    int E, int relb, int nblk, uint4* stage /* [2][256] */)
{
    constexpr int KT = FIN + ED;          // bias row at k=KT; KT+1 <= 8
    const int tid = threadIdx.x;
    const int lane = tid & 63;
    const int wv = tid >> 6;
    const int q = lane >> 4;
    const int col = lane & 15;

    // B fragments for this wave's 2 N-tiles; only quad 0 holds nonzeros (K<=7).
    short8 bfr[2];
#pragma unroll
    for (int nt = 0; nt < 2; ++nt) {
        const int ch = wv * 32 + nt * 16 + col;
        short8 s = (short8)0;
#pragma unroll
        for (int j = 0; j < 8; ++j) {
            const int k = q * 8 + j;
            float w = 0.f;
            if (k < FIN)       w = ldf<ISF32>(Wx, k * H + ch);
            else if (k < KT)   w = ldf<ISF32>(We, (k - FIN) * H + ch);
            else if (k == KT)  w = ldf<ISF32>(bx, ch) + ldf<ISF32>(be, ch);
            s[j] = (short)bfbits(w);
        }
        bfr[nt] = s;
    }
    f32x4 acc0 = (f32x4)0.f, acc1 = (f32x4)0.f;
    const f32x4 zero4 = (f32x4)0.f;

    const int G = (E + 255) >> 8;
    const int chunk = (G + nblk - 1) / nblk;
    const int g0 = relb * chunk;
    const int g1 = min(g0 + chunk, G);
    for (int g = g0; g < g1; ++g) {
        const int buf = g & 1;
        const int base = g << 8;
        const int ecnt = min(256, E - base);
        // stage edge base+tid (1 edge per thread, bf16-packed 16B)
        float f[8];
#pragma unroll
        for (int k = 0; k < 8; ++k) f[k] = 0.f;
        if (tid < ecnt) {
            const int ej = base + tid;
            const int s = src[ej];
            if constexpr (FIN == 4) {
                const float4 xv = ld4<ISF32>(x, s);
                f[0] = xv.x; f[1] = xv.y; f[2] = xv.z; f[3] = xv.w;
            } else {
#pragma unroll
                for (int k = 0; k < FIN; ++k) f[k] = ldf<ISF32>(x, s * FIN + k);
            }
#pragma unroll
            for (int k = 0; k < ED; ++k) f[FIN + k] = ldf<ISF32>(ea, ej * ED + k);
            f[KT] = 1.0f;
        }
        uint4 pk;
        pk.x = pack2(f[0], f[1]); pk.y = pack2(f[2], f[3]);
        pk.z = pack2(f[4], f[5]); pk.w = pack2(f[6], f[7]);
        stage[buf * 256 + tid] = pk;
        __syncthreads();   // stage visible; also guards buf reuse (2 bufs)
        const uint4* st = stage + buf * 256;
#pragma unroll 4
        for (int mt = 0; mt < 16; ++mt) {
            union { short8 s; uint4 u; } au;
            au.u = (uint4){0, 0, 0, 0};
            if (lane < 16) au.u = st[mt * 16 + lane];   // exec-masked A-frag
            f32x4 d0 = __builtin_amdgcn_mfma_f32_16x16x32_bf16(au.s, bfr[0], zero4, 0, 0, 0);
            f32x4 d1 = __builtin_amdgcn_mfma_f32_16x16x32_bf16(au.s, bfr[1], zero4, 0, 0, 0);
            acc0 += __builtin_elementwise_max(d0, zero4);
            acc1 += __builtin_elementwise_max(d1, zero4);
        }
    }
    // fold: 4 regs (edge rows) + cross-quad -> channel sums on lanes 0..15
    float v0 = acc0[0] + acc0[1] + acc0[2] + acc0[3];
    v0 += __shfl_xor(v0, 16, 64);
    v0 += __shfl_xor(v0, 32, 64);
    float v1 = acc1[0] + acc1[1] + acc1[2] + acc1[3];
    v1 += __shfl_xor(v1, 16, 64);
    v1 += __shfl_xor(v1, 32, 64);
    if (lane < 16) {
        part[wv * 32 + col] = v0;        // disjoint per wave: plain stores
        part[wv * 32 + 16 + col] = v1;
    }
}

// ---- component sums of x over nodes ----
template<int FIN, bool ISF32>
__device__ __forceinline__ void mean_body(
    const void* __restrict__ x, float* __restrict__ part, int N,
    int relb, int nblk, float* lds)
{
    const int stride = nblk * 256;
    float acc[FIN];
#pragma unroll
    for (int k = 0; k < FIN; ++k) acc[k] = 0.f;
    for (int n = relb * 256 + threadIdx.x; n < N; n += stride) {
        if constexpr (FIN == 4) {
            const float4 xv = ld4<ISF32>(x, n);
            acc[0] += xv.x; acc[1] += xv.y; acc[2] += xv.z; acc[3] += xv.w;
        } else {
#pragma unroll
            for (int k = 0; k < FIN; ++k) acc[k] += ldf<ISF32>(x, n * FIN + k);
        }
    }
#pragma unroll
    for (int k = 0; k < FIN; ++k) acc[k] = wred(acc[k]);
    if ((threadIdx.x & 63) == 0) {
        const int w = threadIdx.x >> 6;
#pragma unroll
        for (int k = 0; k < 4; ++k) lds[w * 4 + k] = (k < FIN) ? acc[k] : 0.f;
    }
    __syncthreads();
    if (threadIdx.x < 4)
        part[threadIdx.x] = lds[threadIdx.x] + lds[4 + threadIdx.x]
                          + lds[8 + threadIdx.x] + lds[12 + threadIdx.x];
}

// ---- SAGE edge reduction, int4-batched ----
template<bool ISF32>
__device__ __forceinline__ void sage_body(
    const void* __restrict__ x, const int* __restrict__ src,
    const int* __restrict__ dst, const int* __restrict__ cnt,
    float* __restrict__ part, int E, int relb, int nblk, float* lds)
{
    const int tid = threadIdx.x;
    const int nv = E >> 2;
    const int stride = nblk * 256;
    float a0 = 0.f, a1 = 0.f, a2 = 0.f, a3 = 0.f, aw = 0.f;
#pragma unroll 2
    for (int i = relb * 256 + tid; i < nv; i += stride) {
        const int4 s4 = ((const int4*)src)[i];
        const int4 d4 = ((const int4*)dst)[i];
        const int c0 = cnt[d4.x], c1 = cnt[d4.y], c2 = cnt[d4.z], c3 = cnt[d4.w];
        const float4 x0 = ld4<ISF32>(x, s4.x);
        const float4 x1 = ld4<ISF32>(x, s4.y);
        const float4 x2 = ld4<ISF32>(x, s4.z);
        const float4 x3 = ld4<ISF32>(x, s4.w);
        const float i0 = __builtin_amdgcn_rcpf((float)(c0 > 0 ? c0 : 1));
        const float i1 = __builtin_amdgcn_rcpf((float)(c1 > 0 ? c1 : 1));
        const float i2 = __builtin_amdgcn_rcpf((float)(c2 > 0 ? c2 : 1));
        const float i3 = __builtin_amdgcn_rcpf((float)(c3 > 0 ? c3 : 1));
        a0 = fmaf(i0, x0.x, a0); a1 = fmaf(i0, x0.y, a1); a2 = fmaf(i0, x0.z, a2); a3 = fmaf(i0, x0.w, a3); aw += i0;
        a0 = fmaf(i1, x1.x, a0); a1 = fmaf(i1, x1.y, a1); a2 = fmaf(i1, x1.z, a2); a3 = fmaf(i1, x1.w, a3); aw += i1;
        a0 = fmaf(i2, x2.x, a0); a1 = fmaf(i2, x2.y, a1); a2 = fmaf(i2, x2.z, a2); a3 = fmaf(i2, x2.w, a3); aw += i2;
        a0 = fmaf(i3, x3.x, a0); a1 = fmaf(i3, x3.y, a1); a2 = fmaf(i3, x3.z, a2); a3 = fmaf(i3, x3.w, a3); aw += i3;
    }
    a0 = wred(a0); a1 = wred(a1); a2 = wred(a2); a3 = wred(a3); aw = wred(aw);
    if ((tid & 63) == 0) {
        float* w5 = lds + (tid >> 6) * 5;
        w5[0] = a0; w5[1] = a1; w5[2] = a2; w5[3] = a3; w5[4] = aw;
    }
    __syncthreads();
    if (tid < 5)
        part[tid] = lds[tid] + lds[5 + tid] + lds[10 + tid] + lds[15 + tid];
}

// ---- warm: stream final-kernel weights into L2/L3 ----
__device__ __forceinline__ void warm_body(const Par p, int rb, bool f32, float* lds) {
    const void* w[6] = {p.Wn_a, p.Wn_c, p.Wl_tv, p.Wr_tv, p.Wl_log, p.Wr_log};
    const uint4* u = (const uint4*)w[rb];
    const int n16 = (f32 ? (H * H * 4) : (H * H * 2)) / 16;
    uint32_t s = 0;
    for (int i = threadIdx.x; i < n16; i += 256) {
        const uint4 v = u[i];
        s ^= v.x ^ v.y ^ v.z ^ v.w;
    }
    lds[threadIdx.x] = (float)(s & 1);
    __syncthreads();
    if (threadIdx.x == 0) {
        float acc = 0.f;
        for (int i = 0; i < 256; ++i) acc += lds[i];
        p.part_mn[(48 + rb) * 4] = acc;   // dummy sink (rows >= 48 unused)
    }
}

// ---- main: gine_a | gine_c | sage_tv | sage_log | means | warm ----
template<bool ISF32>
__device__ __forceinline__ void main_body(const Par p, uint4* stage, float* red) {
    const int b = blockIdx.x;
    if (b < B_GA) {
        gine_body<3, 3, ISF32>(p.ei_a, p.ea_a, p.x_m, p.We_a, p.be_a, p.Wm, p.bm,
                               p.part_a + b * H, EA, b, B_GA, stage);
    } else if (b < B_GA + B_GC) {
        const int rb = b - B_GA;
        gine_body<4, 1, ISF32>(p.ei_c, p.ea_c, p.x_o, p.We_c, p.be_c, p.Wo, p.bo,
                               p.part_c + rb * H, EC, rb, B_GC, stage);
    } else if (b < B_GA + B_GC + B_TV) {
        const int rb = b - (B_GA + B_GC);
        sage_body<ISF32>(p.x_o, p.ei_tv, p.ei_tv + ET, p.cnt_m,
                         p.part_tv + rb * 8, ET, rb, B_TV, red);
    } else if (b < B_GA + B_GC + B_TV + B_LG) {
        const int rb = b - (B_GA + B_GC + B_TV);
        sage_body<ISF32>(p.x_o, p.ei_log, p.ei_log + EL, p.cnt_o,
                         p.part_lg + rb * 8, EL, rb, B_LG, red);
    } else if (b < B_GA + B_GC + B_TV + B_LG + B_MN) {
        const int rb = b - (B_GA + B_GC + B_TV + B_LG);
        if (rb < 8) mean_body<3, ISF32>(p.x_m, p.part_mn + rb * 4, NM, rb, 8, red);
        else        mean_body<4, ISF32>(p.x_o, p.part_mn + rb * 4, NO, rb - 8, 40, red);
    } else {
        warm_body(p, b - (B_GA + B_GC + B_TV + B_LG + B_MN), ISF32, red);
    }
}

__global__ __launch_bounds__(256) void main_kernel(const Par p) {
    __shared__ __align__(16) uint4 stage[512];   // 8 KB: double-buffered 256 edges
    __shared__ float red[288];
    if (*p.flag) main_body<true >(p, stage, red);
    else         main_body<false>(p, stage, red);
}

// ---- reduce: fold part_a[512][128]->[64][128], part_c[256][128]->[32][128] ----
__global__ __launch_bounds__(256) void reduce_kernel(const Par p) {
    const int b = blockIdx.x;
    const int t = threadIdx.x;
    const int col = t & 127;
    const int half = t >> 7;
    if (b < 64) {
        float s = 0.f;
        const float* src = p.part_a + (b * 8 + half * 4) * H + col;
#pragma unroll
        for (int r = 0; r < 4; ++r) s += src[r * H];
        __shared__ float buf[2][H];
        buf[half][col] = s;
        __syncthreads();
        if (t < H) p.part_a2[b * H + t] = buf[0][t] + buf[1][t];
    } else {
        const int j = b - 64;
        float s = 0.f;
        const float* src = p.part_c + (j * 8 + half * 4) * H + col;
#pragma unroll
        for (int r = 0; r < 4; ++r) s += src[r * H];
        __shared__ float buf2[2][H];
        buf2[half][col] = s;
        __syncthreads();
        if (t < H) p.part_c2[j * H + t] = buf2[0][t] + buf2[1][t];
    }
}

// ---- final: 2 blocks. block 0 -> g_m, block 1 -> g_o ----
template<bool ISF32>
__device__ __forceinline__ void final_body(const Par p) {
    __shared__ float scal[17];
    __shared__ float seg[5][8];
    __shared__ float sh2a[2][H], sh2c[2][H];
    __shared__ float va[H], vb[H], vc2[H], vd[H];
    __shared__ float matp[256];
    const int t = threadIdx.x;

    if (blockIdx.x == 0) {
        // ---- g_m ----
        if (t < 40) {
            const int k = t >> 3, sg = t & 7;
            float s = 0.f;
            const int r0 = sg * (B_TV / 8);
#pragma unroll 8
            for (int r = r0; r < r0 + B_TV / 8; ++r) s += p.part_tv[r * 8 + k];
            seg[k][sg] = s;
        } else if (t >= 64 && t < 67) {
            const int k = t - 64;
            float s = 0.f;
            for (int r = 0; r < 8; ++r) s += p.part_mn[r * 4 + k];
            scal[10 + k] = s;
        }
        __syncthreads();
        if (t < 5) {
            float s = 0.f;
#pragma unroll
            for (int g = 0; g < 8; ++g) s += seg[t][g];
            scal[t] = s;
        }
        __syncthreads();
        if (t < H) {
            float mhm = ldf<ISF32>(p.bm, t);
#pragma unroll
            for (int k = 0; k < 3; ++k)
                mhm = fmaf(scal[10 + k] * (1.f / NM), ldf<ISF32>(p.Wm, k * H + t), mhm);
            float tv = scal[4] * ldf<ISF32>(p.bo, t);
#pragma unroll
            for (int k = 0; k < 4; ++k)
                tv = fmaf(scal[k], ldf<ISF32>(p.Wo, k * H + t), tv);
            va[t] = tv * (1.f / NM);   // vtv
            vb[t] = mhm;               // vmhm
        }
        __syncthreads();
        {
            const int half = t >> 7, tt = t & 127;
            float acc = (half == 0) ? ldf<ISF32>(p.bl_tv, tt) : 0.f;
            const int k0 = half * 64;
#pragma unroll 8
            for (int k = k0; k < k0 + 64; ++k) {
                acc = fmaf(va[k], ldf<ISF32>(p.Wl_tv, k * H + tt), acc);
                acc = fmaf(vb[k], ldf<ISF32>(p.Wr_tv, k * H + tt), acc);
            }
            matp[t] = acc;
        }
        __syncthreads();
        if (t < H) {
            const float r = matp[t] + matp[t + 128];
            if constexpr (ISF32) ((float*)p.out)[t] = r;
            else                 ((bf16*)p.out)[t] = __float2bfloat16(r);
        }
    } else {
        // ---- g_o ----
        {   // column sums of reduced partials (64 + 32 rows)
            const int col = t & 127, half = t >> 7;
            float sA = 0.f;
            const float* pa = p.part_a2 + (half * 32) * H + col;
#pragma unroll 8
            for (int r = 0; r < 32; ++r) sA += pa[r * H];
            sh2a[half][col] = sA;
            float sC = 0.f;
            const float* pc = p.part_c2 + (half * 16) * H + col;
#pragma unroll 8
            for (int r = 0; r < 16; ++r) sC += pc[r * H];
            sh2c[half][col] = sC;
        }
        if (t < 40) {
            const int k = t >> 3, sg = t & 7;
            float s = 0.f;
            const int r0 = sg * (B_LG / 8);
#pragma unroll 8
            for (int r = r0; r < r0 + B_LG / 8; ++r) s += p.part_lg[r * 8 + k];
            seg[k][sg] = s;
        } else if (t >= 64 && t < 68) {
            const int k = t - 64;
            float s = 0.f;
#pragma unroll 8
            for (int r = 8; r < 48; ++r) s += p.part_mn[r * 4 + k];
            scal[13 + k] = s;
        }
        __syncthreads();
        if (t < 5) {
            float s = 0.f;
#pragma unroll
            for (int g = 0; g < 8; ++g) s += seg[t][g];
            scal[5 + t] = s;
        }
        __syncthreads();
        if (t < H) {
            float mho = ldf<ISF32>(p.bo, t);
#pragma unroll
            for (int k = 0; k < 4; ++k)
                mho = fmaf(scal[13 + k] * (1.f / NO), ldf<ISF32>(p.Wo, k * H + t), mho);
            float lg = scal[9] * ldf<ISF32>(p.bo, t);
#pragma unroll
            for (int k = 0; k < 4; ++k)
                lg = fmaf(scal[5 + k], ldf<ISF32>(p.Wo, k * H + t), lg);
            const float sha = sh2a[0][t] + sh2a[1][t];
            const float shc = sh2c[0][t] + sh2c[1][t];
            va[t]  = sha * (1.f / NO) + mho;   // GINE-a vector
            vb[t]  = shc * (1.f / NO) + mho;   // GINE-c vector
            vc2[t] = lg * (1.f / NO);          // vlog
            vd[t]  = mho;                      // vmho
        }
        __syncthreads();
        {
            const int half = t >> 7, tt = t & 127;
            float acc = (half == 0)
                ? ldf<ISF32>(p.bn_a, tt) + ldf<ISF32>(p.bn_c, tt) + ldf<ISF32>(p.bl_log, tt)
                : 0.f;
            const int k0 = half * 64;
#pragma unroll 8
            for (int k = k0; k < k0 + 64; ++k) {
                acc = fmaf(va[k],  ldf<ISF32>(p.Wn_a, k * H + tt), acc);
                acc = fmaf(vb[k],  ldf<ISF32>(p.Wn_c, k * H + tt), acc);
                acc = fmaf(vc2[k], ldf<ISF32>(p.Wl_log, k * H + tt), acc);
                acc = fmaf(vd[k],  ldf<ISF32>(p.Wr_log, k * H + tt), acc);
            }
            matp[t] = acc;
        }
        __syncthreads();
        if (t < H) {
            const float r = (matp[t] + matp[t + 128]) * (1.f / 3.f);
            if constexpr (ISF32) ((float*)p.out)[H + t] = r;
            else                 ((bf16*)p.out)[H + t] = __float2bfloat16(r);
        }
    }
}

__global__ __launch_bounds__(256) void final_kernel(const Par p) {
    if (*p.flag) final_body<true >(p);
    else         final_body<false>(p);
}

extern "C" void kernel_launch(void* const* d_in, const int* in_sizes, int n_in,
                              void* d_out, int out_size, void* d_ws, size_t ws_size,
                              hipStream_t stream) {
    char* ws = (char*)d_ws;
    Par p;
    p.x_m   = d_in[0];  p.x_o   = d_in[1];
    p.ea_a  = d_in[2];  p.ea_c  = d_in[3];
    p.ei_a  = (const int*)d_in[4];
    p.ei_c  = (const int*)d_in[5];
    p.ei_tv = (const int*)d_in[6];
    p.ei_log= (const int*)d_in[7];
    p.Wm = d_in[8];  p.bm = d_in[9];  p.Wo = d_in[10]; p.bo = d_in[11];
    p.Wn_a = d_in[12]; p.bn_a = d_in[13]; p.We_a = d_in[14]; p.be_a = d_in[15];
    p.Wn_c = d_in[16]; p.bn_c = d_in[17]; p.We_c = d_in[18]; p.be_c = d_in[19];
    p.Wl_tv = d_in[20]; p.bl_tv = d_in[21]; p.Wr_tv = d_in[22];
    p.Wl_log = d_in[23]; p.bl_log = d_in[24]; p.Wr_log = d_in[25];

    // Workspace layout (bytes); every region fully written by its owner:
    //   [0,        20480)    cnt_m   int[5000] (padded)
    //   [20480,    430080)   cnt_o   int[102400]
    //   [430080,   430084)   flag
    //   [430592,   1710592)  part_hm u16[128][5000]
    //   [1710592,  4987392)  part_ho u16[16][102400]
    //   [4987392,  5249536)  part_a  float[512][128]
    //   [5249536,  5380608)  part_c  float[256][128]
    //   [5380608,  5396992)  part_tv float[512][8]
    //   [5396992,  5405184)  part_lg float[256][8]
    //   [5405184,  5406048)  part_mn float[54][4]
    //   [5406208,  5438976)  part_a2 float[64][128]
    //   [5438976,  5455360)  part_c2 float[32][128]
    p.cnt_m   = (int*)(ws);
    p.cnt_o   = (int*)(ws + 20480);
    p.flagw   = (int*)(ws + 430080);
    p.flag    = p.flagw;
    p.part_hm = (uint16_t*)(ws + 430592);
    p.part_ho = (uint16_t*)(ws + 1710592);
    p.part_a  = (float*)(ws + 4987392);
    p.part_c  = (float*)(ws + 5249536);
    p.part_tv = (float*)(ws + 5380608);
    p.part_lg = (float*)(ws + 5396992);
    p.part_mn = (float*)(ws + 5405184);
    p.part_a2 = (float*)(ws + 5406208);
    p.part_c2 = (float*)(ws + 5438976);
    p.out  = d_out;

    hist_kernel<<<HIST_BLOCKS, 256, 0, stream>>>(p);    // detect + private hists
    merge_kernel<<<MERGE_BLOCKS, 256, 0, stream>>>(p);  // counts (atomic-free)
    main_kernel<<<MAIN_BLOCKS, 256, 0, stream>>>(p);    // gine(MFMA v2) + sage + means
    reduce_kernel<<<96, 256, 0, stream>>>(p);           // fold gine partials
    final_kernel<<<2, 256, 0, stream>>>(p);             // mat-vecs + output
}